// Round 1
// baseline (1239.331 us; speedup 1.0000x reference)
//
#include <hip/hip_runtime.h>
#include <stdint.h>

typedef unsigned short u16;
typedef u16    u16x8  __attribute__((ext_vector_type(8)));
typedef __bf16 bf16x8 __attribute__((ext_vector_type(8)));
typedef float  f32x4  __attribute__((ext_vector_type(4)));

#define TOKS 50176   // B*H*W = 16*56*56
#define CD   512

__device__ __forceinline__ float bf2f(u16 u) {
    union { unsigned int i; float f; } c; c.i = ((unsigned int)u) << 16; return c.f;
}
__device__ __forceinline__ u16 f2bf(float f) {
    union { float f; unsigned int i; } c; c.f = f;
    unsigned int x = c.i;
    return (u16)((x + 0x7fffu + ((x >> 16) & 1u)) >> 16);
}
__device__ __forceinline__ float gelu_tanh(float x) {
    // jax.nn.gelu approximate=True: 0.5x(1+tanh(0.79788456(x+0.044715x^3)))
    float t = 0.7978845608028654f * (x + 0.044715f * x * x * x);
    float e = __expf(2.0f * t);               // e->inf => th->1 ; e->0 => th->-1
    float th = 1.0f - 2.0f / (e + 1.0f);
    return 0.5f * x * (1.0f + th);
}

// ---------------- weight transpose + cast: src[K][N] f32 -> dst[N][K] bf16 ----
__global__ __launch_bounds__(256)
void k_transpose_cast(const float* __restrict__ src, u16* __restrict__ dst,
                      const int K, const int N)
{
    __shared__ float tile[32][33];
    const int tx = threadIdx.x & 31, ty = threadIdx.x >> 5;  // ty 0..7
    const int n0 = blockIdx.x * 32, k0 = blockIdx.y * 32;
    #pragma unroll
    for (int i = 0; i < 4; ++i) {
        int r = ty + i * 8;
        tile[r][tx] = src[(size_t)(k0 + r) * N + n0 + tx];
    }
    __syncthreads();
    #pragma unroll
    for (int i = 0; i < 4; ++i) {
        int r = ty + i * 8;
        dst[(size_t)(n0 + r) * K + k0 + tx] = f2bf(tile[tx][r]);
    }
}

// ---------------- LayerNorm over C=512, f32 in -> bf16 out ------------------
__global__ __launch_bounds__(256)
void k_layernorm(const float* __restrict__ x, const float* __restrict__ g,
                 const float* __restrict__ bvec, u16* __restrict__ out)
{
    const int l = threadIdx.x & 63;
    const int w = threadIdx.x >> 6;
    const size_t row = (size_t)blockIdx.x * 4 + w;
    const float* xr = x + row * CD + l * 8;
    f32x4 v0 = *(const f32x4*)xr;
    f32x4 v1 = *(const f32x4*)(xr + 4);
    float s = 0.f, sq = 0.f;
    #pragma unroll
    for (int i = 0; i < 4; ++i) { s += v0[i]; sq += v0[i] * v0[i]; }
    #pragma unroll
    for (int i = 0; i < 4; ++i) { s += v1[i]; sq += v1[i] * v1[i]; }
    #pragma unroll
    for (int off = 32; off > 0; off >>= 1) {
        s  += __shfl_xor(s, off);
        sq += __shfl_xor(sq, off);
    }
    const float mean = s * (1.0f / 512.0f);
    const float var  = fmaxf(sq * (1.0f / 512.0f) - mean * mean, 0.0f);
    const float rstd = rsqrtf(var + 1e-6f);
    const int c = l * 8;
    f32x4 g0 = *(const f32x4*)(g + c),    g1 = *(const f32x4*)(g + c + 4);
    f32x4 b0 = *(const f32x4*)(bvec + c), b1 = *(const f32x4*)(bvec + c + 4);
    u16x8 o;
    #pragma unroll
    for (int i = 0; i < 4; ++i) o[i]     = f2bf((v0[i] - mean) * rstd * g0[i] + b0[i]);
    #pragma unroll
    for (int i = 0; i < 4; ++i) o[4 + i] = f2bf((v1[i] - mean) * rstd * g1[i] + b1[i]);
    *(u16x8*)(out + row * CD + c) = o;
}

// ---------------- bf16 GEMM: C[M][N] = A[M][K] @ Bt[N][K]^T + bias ----------
// EPI: 0 = bias -> bf16 ; 1 = bias+gelu -> bf16 ; 2 = bias + f32 residual -> f32
// 128x128 tile, 4 waves (2x2), BK=32, mfma_f32_16x16x32_bf16.
template<int EPI>
__global__ __launch_bounds__(256)
void k_gemm(const u16* __restrict__ A, const u16* __restrict__ Bt,
            const float* __restrict__ bias, const float* __restrict__ resid,
            u16* __restrict__ outb, float* __restrict__ outf,
            const int N, const int K)
{
    __shared__ u16 As[128 * 32];
    __shared__ u16 Bs[128 * 32];
    const int t  = threadIdx.x;
    const int l  = t & 63;
    const int w  = t >> 6;
    const int wr = w >> 1, wc = w & 1;          // 2x2 wave grid, each wave 64x64
    const int m0 = blockIdx.x * 128, n0 = blockIdx.y * 128;
    const int sr = t >> 2;                      // staging row 0..63
    const int sq = t & 3;                       // staging 16B slot
    const int kq = l >> 4;                      // frag k-slot 0..3
    const int fr = l & 15;                      // frag row/col

    const u16* Ap0 = A  + (size_t)(m0 + sr) * K      + sq * 8;
    const u16* Ap1 = A  + (size_t)(m0 + 64 + sr) * K + sq * 8;
    const u16* Bp0 = Bt + (size_t)(n0 + sr) * K      + sq * 8;
    const u16* Bp1 = Bt + (size_t)(n0 + 64 + sr) * K + sq * 8;
    const int wo0 = sr * 32 + sq * 8;
    const int wo1 = (64 + sr) * 32 + sq * 8;

    f32x4 acc[4][4];
    #pragma unroll
    for (int i = 0; i < 4; ++i)
        #pragma unroll
        for (int j = 0; j < 4; ++j) {
            f32x4 z = {0.f, 0.f, 0.f, 0.f};
            acc[i][j] = z;
        }

    for (int k0 = 0; k0 < K; k0 += 32) {
        u16x8 a0 = *(const u16x8*)(Ap0 + k0);
        u16x8 a1 = *(const u16x8*)(Ap1 + k0);
        u16x8 b0 = *(const u16x8*)(Bp0 + k0);
        u16x8 b1 = *(const u16x8*)(Bp1 + k0);
        __syncthreads();
        *(u16x8*)&As[wo0] = a0;
        *(u16x8*)&As[wo1] = a1;
        *(u16x8*)&Bs[wo0] = b0;
        *(u16x8*)&Bs[wo1] = b1;
        __syncthreads();
        bf16x8 af[4], bfv[4];
        #pragma unroll
        for (int mi = 0; mi < 4; ++mi)
            af[mi] = *(const bf16x8*)&As[(wr * 64 + mi * 16 + fr) * 32 + kq * 8];
        #pragma unroll
        for (int ni = 0; ni < 4; ++ni)
            bfv[ni] = *(const bf16x8*)&Bs[(wc * 64 + ni * 16 + fr) * 32 + kq * 8];
        #pragma unroll
        for (int mi = 0; mi < 4; ++mi)
            #pragma unroll
            for (int ni = 0; ni < 4; ++ni)
                acc[mi][ni] = __builtin_amdgcn_mfma_f32_16x16x32_bf16(
                    af[mi], bfv[ni], acc[mi][ni], 0, 0, 0);
    }

    float bv[4];
    #pragma unroll
    for (int ni = 0; ni < 4; ++ni) bv[ni] = bias[n0 + wc * 64 + ni * 16 + fr];

    #pragma unroll
    for (int mi = 0; mi < 4; ++mi) {
        #pragma unroll
        for (int r = 0; r < 4; ++r) {
            const size_t row  = (size_t)(m0 + wr * 64 + mi * 16 + kq * 4 + r);
            const size_t base = row * N + n0 + wc * 64 + fr;
            #pragma unroll
            for (int ni = 0; ni < 4; ++ni) {
                float v = acc[mi][ni][r] + bv[ni];
                if (EPI == 1) v = gelu_tanh(v);
                if (EPI == 2) outf[base + ni * 16] = v + resid[base + ni * 16];
                else          outb[base + ni * 16] = f2bf(v);
            }
        }
    }
}

// ---------------- windowed attention: 1 wave per (window, head) -------------
// qkv: [chunk_tokens][1536] bf16 (q|k|v each 512 cols, head h at h*32).
// Scores scaled by 512^-0.5 (faithful to reference), +rel-pos bias, softmax, PV.
__global__ __launch_bounds__(64)
void k_attn(const u16* __restrict__ qkv, const float* __restrict__ btab,
            u16* __restrict__ o, const int tok_base)
{
    __shared__ float Ss[64 * 53];    // per-lane score rows, stride 53 (odd mod 32)
    const int l    = threadIdx.x;
    const int widl = blockIdx.x >> 4;       // window within chunk (0..127)
    const int head = blockIdx.x & 15;
    const int bl   = widl >> 6;             // batch within chunk (0..1)
    const int g    = widl & 63;
    const int gh   = g >> 3, gw = g & 7;
    const int tok00 = bl * 3136 + gh * 392 + gw * 7;   // local token of (0,0) in window
    const int pl = (l < 49) ? l : 48;
    const int ph = pl / 7, pw = pl - (pl / 7) * 7;
    const int tokl = tok00 + ph * 56 + pw;

    // load own Q row (32 bf16 -> f32)
    float q[32];
    {
        const size_t qoff = (size_t)tokl * 1536 + head * 32;
        #pragma unroll
        for (int i = 0; i < 4; ++i) {
            u16x8 u = *(const u16x8*)(qkv + qoff + i * 8);
            #pragma unroll
            for (int j = 0; j < 8; ++j) q[i * 8 + j] = bf2f(u[j]);
        }
    }

    // pass 1: scores
    float rowmax = -1e30f;
    {
        int j = 0;
        for (int jh = 0; jh < 7; ++jh) {
            for (int jw = 0; jw < 7; ++jw, ++j) {
                const size_t koff = (size_t)(tok00 + jh * 56 + jw) * 1536 + 512 + head * 32;
                float d0 = 0.f, d1 = 0.f, d2 = 0.f, d3 = 0.f;
                #pragma unroll
                for (int i = 0; i < 4; ++i) {
                    u16x8 u = *(const u16x8*)(qkv + koff + i * 8);
                    d0 += q[i * 8 + 0] * bf2f(u[0]); d0 += q[i * 8 + 1] * bf2f(u[1]);
                    d1 += q[i * 8 + 2] * bf2f(u[2]); d1 += q[i * 8 + 3] * bf2f(u[3]);
                    d2 += q[i * 8 + 4] * bf2f(u[4]); d2 += q[i * 8 + 5] * bf2f(u[5]);
                    d3 += q[i * 8 + 6] * bf2f(u[6]); d3 += q[i * 8 + 7] * bf2f(u[7]);
                }
                const float bias = btab[(size_t)((ph - jh + 6) * 13 + (pw - jw + 6)) * 16 + head];
                const float sc = (d0 + d1 + d2 + d3) * 0.04419417382415922f + bias;
                rowmax = fmaxf(rowmax, sc);
                Ss[l * 53 + j] = sc;
            }
        }
    }

    // pass 2: softmax numerators + denominator
    float sum = 0.f;
    for (int j = 0; j < 49; ++j) {
        float p = __expf(Ss[l * 53 + j] - rowmax);
        sum += p;
        Ss[l * 53 + j] = p;
    }

    // pass 3: PV
    float oa[32];
    #pragma unroll
    for (int i = 0; i < 32; ++i) oa[i] = 0.f;
    {
        int j = 0;
        for (int jh = 0; jh < 7; ++jh) {
            for (int jw = 0; jw < 7; ++jw, ++j) {
                const size_t voff = (size_t)(tok00 + jh * 56 + jw) * 1536 + 1024 + head * 32;
                const float p = Ss[l * 53 + j];
                #pragma unroll
                for (int i = 0; i < 4; ++i) {
                    u16x8 u = *(const u16x8*)(qkv + voff + i * 8);
                    #pragma unroll
                    for (int jj = 0; jj < 8; ++jj) oa[i * 8 + jj] += p * bf2f(u[jj]);
                }
            }
        }
    }

    if (l < 49) {
        const float inv = 1.0f / sum;
        const size_t obase = (size_t)(tok_base + tokl) * CD + head * 32;
        #pragma unroll
        for (int i = 0; i < 4; ++i) {
            u16x8 u;
            #pragma unroll
            for (int jj = 0; jj < 8; ++jj) u[jj] = f2bf(oa[i * 8 + jj] * inv);
            *(u16x8*)(o + obase + i * 8) = u;
        }
    }
}

// ---------------------------------------------------------------------------
extern "C" void kernel_launch(void* const* d_in, const int* in_sizes, int n_in,
                              void* d_out, int out_size, void* d_ws, size_t ws_size,
                              hipStream_t stream)
{
    (void)in_sizes; (void)n_in; (void)out_size; (void)ws_size;
    const float* x     = (const float*)d_in[0];
    const float* ln1_s = (const float*)d_in[1];
    const float* ln1_b = (const float*)d_in[2];
    const float* w_qkv = (const float*)d_in[3];
    const float* b_qkv = (const float*)d_in[4];
    const float* btab  = (const float*)d_in[5];
    const float* w_mrg = (const float*)d_in[6];
    const float* b_mrg = (const float*)d_in[7];
    const float* ln2_s = (const float*)d_in[8];
    const float* ln2_b = (const float*)d_in[9];
    const float* w1    = (const float*)d_in[10];
    const float* b1    = (const float*)d_in[11];
    const float* w2    = (const float*)d_in[12];
    const float* b2    = (const float*)d_in[13];
    float* out = (float*)d_out;

    // ---- workspace layout (total ~318.4 MiB) ----
    u16* wqkvT = (u16*)d_ws;                                // [1536][512]
    u16* wmrgT = wqkvT + (size_t)1536 * 512;                // [512][512]
    u16* w1T   = wmrgT + (size_t)512 * 512;                 // [2048][512]
    u16* w2T   = w1T   + (size_t)2048 * 512;                // [512][2048]
    u16* hbuf  = w2T   + (size_t)512 * 2048;                // [TOKS][512] h, then o
    u16* mbuf  = hbuf  + (size_t)TOKS * 512;                // [TOKS][512] LN2 out
    float* y1  = (float*)(mbuf + (size_t)TOKS * 512);       // [TOKS][512] f32 residual
    u16* qkvc  = (u16*)(y1 + (size_t)TOKS * 512);           // [6272][1536] chunk
    u16* hidc  = qkvc + (size_t)6272 * 1536;                // [25088][2048] chunk

    dim3 B256(256);

    // weights: transpose + cast to bf16 [N][K]
    k_transpose_cast<<<dim3(48, 16), B256, 0, stream>>>(w_qkv, wqkvT, 512, 1536);
    k_transpose_cast<<<dim3(16, 16), B256, 0, stream>>>(w_mrg, wmrgT, 512, 512);
    k_transpose_cast<<<dim3(64, 16), B256, 0, stream>>>(w1,   w1T,   512, 2048);
    k_transpose_cast<<<dim3(16, 64), B256, 0, stream>>>(w2,   w2T,   2048, 512);

    // LN1: x -> h (bf16)
    k_layernorm<<<dim3(TOKS / 4), B256, 0, stream>>>(x, ln1_s, ln1_b, hbuf);

    // QKV GEMM + attention, chunked over 2 batches (6272 tokens = 49*128 rows)
    for (int c = 0; c < 8; ++c) {
        const size_t tb = (size_t)c * 6272;
        k_gemm<0><<<dim3(49, 12), B256, 0, stream>>>(
            hbuf + tb * 512, wqkvT, b_qkv, nullptr, qkvc, nullptr, 1536, 512);
        k_attn<<<dim3(128 * 16), dim3(64), 0, stream>>>(qkvc, btab, hbuf, (int)tb);
    }

    // merge GEMM + residual(x) -> y1 (f32)
    k_gemm<2><<<dim3(392, 4), B256, 0, stream>>>(
        hbuf, wmrgT, b_mrg, x, nullptr, y1, 512, 512);

    // LN2: y1 -> m (bf16)
    k_layernorm<<<dim3(TOKS / 4), B256, 0, stream>>>(y1, ln2_s, ln2_b, mbuf);

    // MLP, chunked over 25088 rows (=196*128)
    for (int c = 0; c < 2; ++c) {
        const size_t rb = (size_t)c * 25088;
        k_gemm<1><<<dim3(196, 16), B256, 0, stream>>>(
            mbuf + rb * 512, w1T, b1, nullptr, hidc, nullptr, 2048, 512);
        k_gemm<2><<<dim3(196, 4), B256, 0, stream>>>(
            hidc, w2T, b2, y1 + rb * 512, nullptr, out + rb * 512, 512, 2048);
    }
}